// Round 10
// baseline (94.772 us; speedup 1.0000x reference)
//
#include <hip/hip_runtime.h>

// CompactBilinearPooling via count-sketch + FFT circular conv (B=256, D=4096, N=16384).
// R10 = R8 (verified correct, ~35us kernel) + VOP3P for add/sub ONLY:
//   pk_add = v_pk_add_f32                     (no modifiers)
//   pk_sub = v_pk_add_f32 neg_lo:[0,1] neg_hi:[0,1]  (canonical LLVM packed-fsub)
// R9's op_sel-based packed cmul FAILED (absmax 68.75) — op_sel/NEG interaction
// on pk-f32 is not as documented-assumed; cmul stays scalar C. No op_sel used.
// Structure/addressing UNCHANGED from R8: two 8192 fwd FFTs (even/odd pack),
// fused unpack+product+pretwiddle pairing, one 8192 inverse, fused radix-2
// float4 store. Hoisted swizzle bases, conflict-free lanes, trivial twiddles.
// 8-live float2 discipline (R5-proven): VGPR<=64, no scratch spill.

typedef float v2 __attribute__((ext_vector_type(2)));

#define N1      8192
#define BLOCK   1024
#define DIM     4096
#define PI_F    3.14159265358979323846f
#define RS2     0.70710678118654752f
#define SLOT(e) ((e) ^ (((e) >> 4) & 15))
#define REV13(x) ((int)(__brev((unsigned)(x)) >> 19))
#define WAVE_FENCE() __asm__ volatile("s_waitcnt lgkmcnt(0)" ::: "memory")

static __device__ __forceinline__ v2 pk_add(v2 a, v2 b) {
    v2 d;
    asm("v_pk_add_f32 %0, %1, %2" : "=v"(d) : "v"(a), "v"(b));
    return d;
}
static __device__ __forceinline__ v2 pk_sub(v2 a, v2 b) {
    v2 d;
    asm("v_pk_add_f32 %0, %1, %2 neg_lo:[0,1] neg_hi:[0,1]" : "=v"(d) : "v"(a), "v"(b));
    return d;
}
// cmul in scalar C (R8-verified). No op_sel asm — R9 proved it wrong on HW.
static __device__ __forceinline__ v2 cmul(v2 a, v2 b) {
    return (v2){a.x * b.x - a.y * b.y, a.x * b.y + a.y * b.x};
}
static __device__ __forceinline__ v2 csqr(v2 a) { return cmul(a, a); }
static __device__ __forceinline__ v2 expi(float phi) {
    float s, c; __sincosf(phi, &s, &c); return (v2){c, s};
}

// Radix-8 DIF (stages 4S,2S,S), r[j] at base+j*S, phi = -pi*k/(4S).
static __device__ __forceinline__ void fft8_dif(v2* r, float phi) {
    v2 W2 = expi(phi), W1 = csqr(W2), W0 = csqr(W1);
    v2 W[3] = {W0, W1, W2};
    #pragma unroll
    for (int p = 2; p >= 0; --p) {
        #pragma unroll
        for (int h = 0; h < 4; ++h) {
            const int jp = h & ((1 << p) - 1);
            const int j  = ((h >> p) << (p + 1)) | jp;
            const int ci = jp << (2 - p);
            v2 Wp = W[p], T;
            if (ci == 0)      T = Wp;
            else if (ci == 2) T = (v2){Wp.y, -Wp.x};            // * (0,-1)
            else if (ci == 1) T = cmul(Wp, (v2){RS2, -RS2});
            else              T = cmul(Wp, (v2){-RS2, -RS2});   // ci==3
            v2 a = r[j], bb = r[j + (1 << p)];
            r[j] = pk_add(a, bb);
            r[j + (1 << p)] = cmul(pk_sub(a, bb), T);
        }
    }
}

// Radix-8 DIT (stages S,2S,4S), phi = +pi*k/(4S).
static __device__ __forceinline__ void fft8_dit(v2* r, float phi) {
    v2 W2 = expi(phi), W1 = csqr(W2), W0 = csqr(W1);
    v2 W[3] = {W0, W1, W2};
    #pragma unroll
    for (int p = 0; p <= 2; ++p) {
        #pragma unroll
        for (int h = 0; h < 4; ++h) {
            const int jp = h & ((1 << p) - 1);
            const int j  = ((h >> p) << (p + 1)) | jp;
            const int ci = jp << (2 - p);
            v2 Wp = W[p], T;
            if (ci == 0)      T = Wp;
            else if (ci == 2) T = (v2){-Wp.y, Wp.x};            // * (0,1)
            else if (ci == 1) T = cmul(Wp, (v2){RS2, RS2});
            else              T = cmul(Wp, (v2){-RS2, RS2});
            v2 a = r[j], bb = cmul(r[j + (1 << p)], T);
            r[j]            = pk_add(a, bb);
            r[j + (1 << p)] = pk_sub(a, bb);
        }
    }
}

// Radix-8 DIT with k=0 (W=1): pure-constant twiddles.
static __device__ __forceinline__ void fft8_dit0(v2* r) {
    #pragma unroll
    for (int p = 0; p <= 2; ++p) {
        #pragma unroll
        for (int h = 0; h < 4; ++h) {
            const int jp = h & ((1 << p) - 1);
            const int j  = ((h >> p) << (p + 1)) | jp;
            const int ci = jp << (2 - p);
            v2 x = r[j + (1 << p)], bb;
            if (ci == 0)      bb = x;
            else if (ci == 2) bb = (v2){-x.y, x.x};
            else if (ci == 1) bb = cmul(x, (v2){RS2, RS2});
            else              bb = cmul(x, (v2){-RS2, RS2});
            v2 a = r[j];
            r[j] = pk_add(a, bb); r[j + (1 << p)] = pk_sub(a, bb);
        }
    }
}

// Radix-4 DIF (stages 2S,S) with given W1 = e^{-i pi k/(2S)}.
static __device__ __forceinline__ void fft4_difW(v2* r, v2 W1) {
    v2 W0 = csqr(W1);
    v2 a, bb;
    a = r[0]; bb = r[2]; r[0] = pk_add(a, bb); r[2] = cmul(pk_sub(a, bb), W1);
    a = r[1]; bb = r[3]; r[1] = pk_add(a, bb);
    { v2 d = pk_sub(a, bb); r[3] = cmul(d, (v2){W1.y, -W1.x}); }  // W1*(-i)
    a = r[0]; bb = r[1]; r[0] = pk_add(a, bb); r[1] = cmul(pk_sub(a, bb), W0);
    a = r[2]; bb = r[3]; r[2] = pk_add(a, bb); r[3] = cmul(pk_sub(a, bb), W0);
}
// Radix-4 DIF, k = 0 (no twiddles).
static __device__ __forceinline__ void fft4_dif0(v2* r) {
    v2 a, bb;
    a = r[0]; bb = r[2]; r[0] = pk_add(a, bb); r[2] = pk_sub(a, bb);
    a = r[1]; bb = r[3]; r[1] = pk_add(a, bb);
    { v2 d = pk_sub(a, bb); r[3] = (v2){d.y, -d.x}; }
    a = r[0]; bb = r[1]; r[0] = pk_add(a, bb); r[1] = pk_sub(a, bb);
    a = r[2]; bb = r[3]; r[2] = pk_add(a, bb); r[3] = pk_sub(a, bb);
}

// Fused rfft-unpack + product + irfft-pretwiddle (R6-verified formulas).
static __device__ __forceinline__ void pair_slot(v2* zz, int j) {
    const int k  = REV13(j);
    const int kp = (N1 - k) & (N1 - 1);
    const int j2 = REV13(kp);
    v2 A = zz[SLOT(j)], B = zz[SLOT(j2)];
    v2 C = zz[N1 + SLOT(j)], D = zz[N1 + SLOT(j2)];
    v2 E  = (v2){0.5f * (A.x + B.x),  0.5f * (A.y - B.y)};
    v2 O  = (v2){0.5f * (A.y + B.y), -0.5f * (A.x - B.x)};
    v2 F  = (v2){0.5f * (C.x + D.x),  0.5f * (C.y - D.y)};
    v2 Ov = (v2){0.5f * (C.y + D.y), -0.5f * (C.x - D.x)};
    v2 Tm = expi(-PI_F * (float)k * (1.f / 8192.f));
    v2 u = cmul(Tm, O), v = cmul(Tm, Ov);
    v2 G = cmul(pk_add(E, u), pk_add(F, v));
    v2 H = cmul(pk_sub(E, u), pk_sub(F, v));
    v2 S  = (v2){0.5f * (G.x + H.x), 0.5f * (G.y + H.y)};
    v2 gh = pk_sub(G, H);
    v2 t2 = cmul((v2){Tm.x, -Tm.y}, gh);
    v2 Dv = (v2){-0.5f * t2.y, 0.5f * t2.x};
    zz[SLOT(j)]  = pk_add(S, Dv);
    zz[SLOT(j2)] = (v2){S.x - Dv.x, -(S.y - Dv.y)};
}

__launch_bounds__(BLOCK, 4)
__global__ void cbp_fft_kernel(const float* __restrict__ x1,
                               const float* __restrict__ x2,
                               const int* __restrict__ h1,
                               const float* __restrict__ s1,
                               float* __restrict__ out) {
    __shared__ v2 zz[2 * N1];   // c1 | c2, 128 KB
    const int tid = threadIdx.x;
    const int l   = tid & 63;
    const int b   = blockIdx.x;
    float* zf = (float*)zz;

    // ---- zero both sketches ----
    #pragma unroll
    for (int j = 0; j < 16; ++j) zz[tid + (j << 10)] = (v2){0.f, 0.f};
    __syncthreads();

    // ---- count-sketch scatter (random buckets: full SLOT) ----
    const float* x1r = x1 + (size_t)b * DIM;
    const float* x2r = x2 + (size_t)b * DIM;
    #pragma unroll
    for (int i = 0; i < DIM / BLOCK; ++i) {
        int d = tid + (i << 10);
        float s = s1[d];
        int   h = h1[d];
        int  fi = (SLOT(h >> 1) << 1) | (h & 1);
        atomicAdd(&zf[fi], s * x1r[d]);
        atomicAdd(&zf[2 * N1 + fi], s * x2r[d]);
    }
    __syncthreads();

    // ======== forward: two independent 8192-pt DIF FFTs ========
    const int half = tid >> 9;
    const int tt   = tid & 511;
    const int hw   = tt >> 6;        // half-wave index 0..7
    v2* Ah = zz + half * N1;

    // P1 (S=1024): slot(k + j*1024) = (k ^ ((k>>4)&15)) + j*1024
    #pragma unroll 1
    for (int q = 0; q < 2; ++q) {
        int k  = tt + (q << 9);
        int bs = k ^ ((k >> 4) & 15);
        v2 r[8];
        #pragma unroll
        for (int j = 0; j < 8; ++j) r[j] = Ah[bs + (j << 10)];
        fft8_dif(r, (float)k * (-PI_F / 4096.f));
        #pragma unroll
        for (int j = 0; j < 8; ++j) Ah[bs + (j << 10)] = r[j];
    }
    __syncthreads();

    // P2 (S=128, wave-private): slot = (bE ^ 8*(j&1)) + 128j
    #pragma unroll 1
    for (int q = 0; q < 2; ++q) {
        int kk = (tt & 63) + (q << 6);
        int bE = ((hw << 10) + kk) ^ (kk >> 4);
        int bO = bE ^ 8;
        v2 r[8];
        #pragma unroll
        for (int j = 0; j < 8; ++j) r[j] = Ah[((j & 1) ? bO : bE) + (j << 7)];
        fft8_dif(r, (float)kk * (-PI_F / 512.f));
        #pragma unroll
        for (int j = 0; j < 8; ++j) Ah[((j & 1) ? bO : bE) + (j << 7)] = r[j];
    }
    WAVE_FENCE();

    // P3 (S=16, wave-private, conflict-free): slot = (a0 ^ j) + 16j
    #pragma unroll 1
    for (int q = 0; q < 2; ++q) {
        int g  = (hw << 3) + ((l >> 4) << 1) + q;
        int kf = l & 15;
        int a0 = (g << 7) + (kf ^ (q << 3));
        v2 r[8];
        #pragma unroll
        for (int j = 0; j < 8; ++j) r[j] = Ah[(a0 ^ j) + (j << 4)];
        fft8_dif(r, (float)kf * (-PI_F / 64.f));
        #pragma unroll
        for (int j = 0; j < 8; ++j) Ah[(a0 ^ j) + (j << 4)] = r[j];
    }
    WAVE_FENCE();

    // P4/P5 on thread-private 16-span: slot(span*16+i) = sbase ^ i
    {
        const int span  = (hw << 6) + (l & 15) + ((l >> 4) << 4);
        const int sbase = (span << 4) + (span & 15);
        // P4: radix-4 stride 4, W1 = e^{-i pi k4/8} via selects
        #pragma unroll 1
        for (int k4 = 0; k4 < 4; ++k4) {
            float c = (k4 & 1) ? ((k4 & 2) ? 0.38268343f : 0.92387953f)
                               : ((k4 & 2) ? 0.70710678f : 1.f);
            float s = (k4 & 1) ? ((k4 & 2) ? -0.92387953f : -0.38268343f)
                               : ((k4 & 2) ? -0.70710678f : 0.f);
            int sb = sbase ^ k4;
            v2 r[4];
            #pragma unroll
            for (int j = 0; j < 4; ++j) r[j] = Ah[sb ^ (j << 2)];
            fft4_difW(r, (v2){c, s});
            #pragma unroll
            for (int j = 0; j < 4; ++j) Ah[sb ^ (j << 2)] = r[j];
        }
        WAVE_FENCE();
        // P5: radix-4 stride 1, no twiddle
        #pragma unroll 1
        for (int q = 0; q < 4; ++q) {
            int sb = sbase ^ (q << 2);
            v2 r[4];
            #pragma unroll
            for (int j = 0; j < 4; ++j) r[j] = Ah[sb ^ j];
            fft4_dif0(r);
            #pragma unroll
            for (int j = 0; j < 4; ++j) Ah[sb ^ j] = r[j];
        }
    }
    __syncthreads();

    // ======== fused pairing (R6-verified) ========
    #pragma unroll 1
    for (int i = 0; i < 4; ++i) pair_slot(zz, (tid + (i << 10)) << 1);
    if (tid == 0) pair_slot(zz, 1);   // k = 4096 self-pair position
    __syncthreads();

    // ======== inverse: one 8192-pt DIT IFFT ========
    // P1' (S=1, thread-private 8-span): slot(tid*8+i) = B1 ^ i
    {
        int B1 = (tid << 3) ^ ((tid >> 1) & 15);
        v2 r[8];
        #pragma unroll
        for (int i = 0; i < 8; ++i) r[i] = zz[B1 ^ i];
        fft8_dit0(r);
        #pragma unroll
        for (int i = 0; i < 8; ++i) zz[B1 ^ i] = r[i];
    }
    WAVE_FENCE();
    // P2' (S=8, wave-private) — full SLOT
    {
        int g = tid >> 3, k = tid & 7;
        int base = (g << 6) + k;
        v2 r[8];
        #pragma unroll
        for (int j = 0; j < 8; ++j) r[j] = zz[SLOT(base + (j << 3))];
        fft8_dit(r, (float)k * (PI_F / 32.f));
        #pragma unroll
        for (int j = 0; j < 8; ++j) zz[SLOT(base + (j << 3))] = r[j];
    }
    WAVE_FENCE();
    // P3' (S=64, wave-private): 4 bases + 64j immediates
    {
        int k = tid & 63;
        int base0 = ((tid >> 6) << 9) + (k & ~15);
        int Kh = k >> 4, K15 = k & 15;
        int B0  = base0 + (K15 ^ Kh);
        int Bm1 = base0 + (K15 ^ (Kh + 4));
        int Bm2 = base0 + (K15 ^ (Kh + 8));
        int Bm3 = base0 + (K15 ^ (Kh + 12));
        v2 r[8];
        r[0] = zz[B0];        r[1] = zz[Bm1 + 64];
        r[2] = zz[Bm2 + 128]; r[3] = zz[Bm3 + 192];
        r[4] = zz[B0 + 256];  r[5] = zz[Bm1 + 320];
        r[6] = zz[Bm2 + 384]; r[7] = zz[Bm3 + 448];
        fft8_dit(r, (float)k * (PI_F / 256.f));
        zz[B0]        = r[0]; zz[Bm1 + 64]  = r[1];
        zz[Bm2 + 128] = r[2]; zz[Bm3 + 192] = r[3];
        zz[B0 + 256]  = r[4]; zz[Bm1 + 320] = r[5];
        zz[Bm2 + 384] = r[6]; zz[Bm3 + 448] = r[7];
    }
    __syncthreads();
    // P4' (S=512): slot = ((g*4096+k) ^ ((k>>4)&15)) + 512j
    {
        int g = tid >> 9, k = tid & 511;
        int bp = ((g << 12) + k) ^ ((k >> 4) & 15);
        v2 r[8];
        #pragma unroll
        for (int j = 0; j < 8; ++j) r[j] = zz[bp + (j << 9)];
        fft8_dit(r, (float)k * (PI_F / 2048.f));
        #pragma unroll
        for (int j = 0; j < 8; ++j) zz[bp + (j << 9)] = r[j];
    }
    __syncthreads();

    // P5': final radix-2 + coalesced float4 stores.
    // slot(tid*4+d) = b5 ^ d (XOR — R8 fix); slot(n+4096) = slot(n) + 4096.
    float* outr = out + (size_t)b * (2 * N1);
    const float inv_n1 = 1.0f / (float)N1;
    const int b5 = (tid << 2) ^ ((tid >> 2) & 15);
    #pragma unroll 1
    for (int i = 0; i < 2; ++i) {
        v2 lo[2], hi[2];
        #pragma unroll
        for (int s2 = 0; s2 < 2; ++s2) {
            int d5 = (i << 1) + s2;
            int n  = (tid << 2) + d5;
            v2 a  = zz[b5 ^ d5];
            v2 bb = zz[(b5 ^ d5) + 4096];
            v2 T  = expi(PI_F * (float)n * (1.f / 4096.f));
            v2 tb = cmul(T, bb);
            lo[s2] = pk_add(a, tb);
            hi[s2] = pk_sub(a, tb);
        }
        float4 vlo = make_float4(lo[0].x * inv_n1, lo[0].y * inv_n1,
                                 lo[1].x * inv_n1, lo[1].y * inv_n1);
        float4 vhi = make_float4(hi[0].x * inv_n1, hi[0].y * inv_n1,
                                 hi[1].x * inv_n1, hi[1].y * inv_n1);
        *(float4*)(outr + (tid << 3) + (i << 2)) = vlo;
        *(float4*)(outr + N1 + (tid << 3) + (i << 2)) = vhi;
    }
}

extern "C" void kernel_launch(void* const* d_in, const int* in_sizes, int n_in,
                              void* d_out, int out_size, void* d_ws, size_t ws_size,
                              hipStream_t stream) {
    const float* x1 = (const float*)d_in[0];
    const float* x2 = (const float*)d_in[1];
    const int*   h1 = (const int*)d_in[2];
    const float* s1 = (const float*)d_in[3];
    float* out = (float*)d_out;
    const int B = in_sizes[0] / DIM;   // 256
    cbp_fft_kernel<<<B, BLOCK, 0, stream>>>(x1, x2, h1, s1, out);
}

// Round 12
// 94.052 us; speedup vs baseline: 1.0077x; 1.0077x over previous
//
#include <hip/hip_runtime.h>

// CompactBilinearPooling via count-sketch + FFT circular conv (B=256, D=4096, N=16384).
// R12 = R10 (verified) + two changes:
//  (1) WAVE_FENCE restored to s_waitcnt lgkmcnt(0). R11 proved the HW drain is
//      REQUIRED: compiler-only fences raced intermittently (post-timing absmax
//      40.5) — LDS write->read same-wave needs the drain on gfx950.
//  (2) fwd P4+P5 fused into one constant-twiddle 16-pt DIF on the thread-
//      private 16-span (algebra: P4[r4,S=4,W1=e^{-i pi k4/8}] o P5[r4,S=1]
//      == plain 16-pt DIF, stage twiddles e^{-i pi i/8}, e^{-i pi i/4},
//      {1,-i} — all literals; same slots sbase^i). Saves 32 b64 LDS ops,
//      one drain, and the select-twiddle chain. Spill watch: FETCH/WRITE.
// Everything else identical to R10: two 8192 fwd FFTs (even/odd pack), fused
// unpack+product+pretwiddle pairing, one 8192 inverse, fused radix-2 float4
// store; hoisted swizzle bases; pk_add/pk_sub VOP3P; scalar cmul.

typedef float v2 __attribute__((ext_vector_type(2)));

#define N1      8192
#define BLOCK   1024
#define DIM     4096
#define PI_F    3.14159265358979323846f
#define RS2     0.70710678118654752f
#define SLOT(e) ((e) ^ (((e) >> 4) & 15))
#define REV13(x) ((int)(__brev((unsigned)(x)) >> 19))
// HW drain REQUIRED for wave-private LDS pass boundaries (R11 raced without).
#define WAVE_FENCE() __asm__ volatile("s_waitcnt lgkmcnt(0)" ::: "memory")

static __device__ __forceinline__ v2 pk_add(v2 a, v2 b) {
    v2 d;
    asm("v_pk_add_f32 %0, %1, %2" : "=v"(d) : "v"(a), "v"(b));
    return d;
}
static __device__ __forceinline__ v2 pk_sub(v2 a, v2 b) {
    v2 d;
    asm("v_pk_add_f32 %0, %1, %2 neg_lo:[0,1] neg_hi:[0,1]" : "=v"(d) : "v"(a), "v"(b));
    return d;
}
// cmul in scalar C (R8-verified). No op_sel asm — R9 proved it wrong on HW.
static __device__ __forceinline__ v2 cmul(v2 a, v2 b) {
    return (v2){a.x * b.x - a.y * b.y, a.x * b.y + a.y * b.x};
}
static __device__ __forceinline__ v2 cmulc(v2 a, float cr, float ci) {
    return (v2){a.x * cr - a.y * ci, a.x * ci + a.y * cr};
}
static __device__ __forceinline__ v2 csqr(v2 a) { return cmul(a, a); }
static __device__ __forceinline__ v2 expi(float phi) {
    float s, c; __sincosf(phi, &s, &c); return (v2){c, s};
}

// Radix-8 DIF (stages 4S,2S,S), r[j] at base+j*S, phi = -pi*k/(4S).
static __device__ __forceinline__ void fft8_dif(v2* r, float phi) {
    v2 W2 = expi(phi), W1 = csqr(W2), W0 = csqr(W1);
    v2 W[3] = {W0, W1, W2};
    #pragma unroll
    for (int p = 2; p >= 0; --p) {
        #pragma unroll
        for (int h = 0; h < 4; ++h) {
            const int jp = h & ((1 << p) - 1);
            const int j  = ((h >> p) << (p + 1)) | jp;
            const int ci = jp << (2 - p);
            v2 Wp = W[p], T;
            if (ci == 0)      T = Wp;
            else if (ci == 2) T = (v2){Wp.y, -Wp.x};            // * (0,-1)
            else if (ci == 1) T = cmul(Wp, (v2){RS2, -RS2});
            else              T = cmul(Wp, (v2){-RS2, -RS2});   // ci==3
            v2 a = r[j], bb = r[j + (1 << p)];
            r[j] = pk_add(a, bb);
            r[j + (1 << p)] = cmul(pk_sub(a, bb), T);
        }
    }
}

// Radix-8 DIT (stages S,2S,4S), phi = +pi*k/(4S).
static __device__ __forceinline__ void fft8_dit(v2* r, float phi) {
    v2 W2 = expi(phi), W1 = csqr(W2), W0 = csqr(W1);
    v2 W[3] = {W0, W1, W2};
    #pragma unroll
    for (int p = 0; p <= 2; ++p) {
        #pragma unroll
        for (int h = 0; h < 4; ++h) {
            const int jp = h & ((1 << p) - 1);
            const int j  = ((h >> p) << (p + 1)) | jp;
            const int ci = jp << (2 - p);
            v2 Wp = W[p], T;
            if (ci == 0)      T = Wp;
            else if (ci == 2) T = (v2){-Wp.y, Wp.x};            // * (0,1)
            else if (ci == 1) T = cmul(Wp, (v2){RS2, RS2});
            else              T = cmul(Wp, (v2){-RS2, RS2});
            v2 a = r[j], bb = cmul(r[j + (1 << p)], T);
            r[j]            = pk_add(a, bb);
            r[j + (1 << p)] = pk_sub(a, bb);
        }
    }
}

// Radix-8 DIT with k=0 (W=1): pure-constant twiddles.
static __device__ __forceinline__ void fft8_dit0(v2* r) {
    #pragma unroll
    for (int p = 0; p <= 2; ++p) {
        #pragma unroll
        for (int h = 0; h < 4; ++h) {
            const int jp = h & ((1 << p) - 1);
            const int j  = ((h >> p) << (p + 1)) | jp;
            const int ci = jp << (2 - p);
            v2 x = r[j + (1 << p)], bb;
            if (ci == 0)      bb = x;
            else if (ci == 2) bb = (v2){-x.y, x.x};
            else if (ci == 1) bb = cmul(x, (v2){RS2, RS2});
            else              bb = cmul(x, (v2){-RS2, RS2});
            v2 a = r[j];
            r[j] = pk_add(a, bb); r[j + (1 << p)] = pk_sub(a, bb);
        }
    }
}

// Radix-4 DIF, k = 0 (no twiddles): stages m=2 then m=1 on a consecutive quad.
static __device__ __forceinline__ void fft4_dif0(v2* r) {
    v2 a, bb;
    a = r[0]; bb = r[2]; r[0] = pk_add(a, bb); r[2] = pk_sub(a, bb);
    a = r[1]; bb = r[3]; r[1] = pk_add(a, bb);
    { v2 d = pk_sub(a, bb); r[3] = (v2){d.y, -d.x}; }
    a = r[0]; bb = r[1]; r[0] = pk_add(a, bb); r[1] = pk_sub(a, bb);
    a = r[2]; bb = r[3]; r[2] = pk_add(a, bb); r[3] = pk_sub(a, bb);
}

// Fused 16-pt DIF, constant twiddles == P4 (r4 S=4, W1=e^{-i pi k4/8}) then
// P5 (r4 S=1). Same butterflies, same placement (element i -> slot sbase^i).
static __device__ __forceinline__ void fft16_dif0(v2* r) {
    const float C1 = 0.92387953f, S1 = 0.38268343f;   // e^{-i pi/8} = (C1,-S1)
    // stage m=8: (i, i+8), twiddle e^{-i pi i/8}
    {
        v2 a, d;
        a = r[0]; d = pk_sub(a, r[8]);  r[0] = pk_add(a, r[8]);  r[8]  = d;
        a = r[1]; d = pk_sub(a, r[9]);  r[1] = pk_add(a, r[9]);  r[9]  = cmulc(d,  C1, -S1);
        a = r[2]; d = pk_sub(a, r[10]); r[2] = pk_add(a, r[10]); r[10] = cmulc(d,  RS2, -RS2);
        a = r[3]; d = pk_sub(a, r[11]); r[3] = pk_add(a, r[11]); r[11] = cmulc(d,  S1, -C1);
        a = r[4]; d = pk_sub(a, r[12]); r[4] = pk_add(a, r[12]); r[12] = (v2){d.y, -d.x};
        a = r[5]; d = pk_sub(a, r[13]); r[5] = pk_add(a, r[13]); r[13] = cmulc(d, -S1, -C1);
        a = r[6]; d = pk_sub(a, r[14]); r[6] = pk_add(a, r[14]); r[14] = cmulc(d, -RS2, -RS2);
        a = r[7]; d = pk_sub(a, r[15]); r[7] = pk_add(a, r[15]); r[15] = cmulc(d, -C1, -S1);
    }
    // stage m=4: (h*8+i, h*8+i+4), twiddle e^{-i pi i/4}
    #pragma unroll
    for (int h = 0; h < 2; ++h) {
        v2 a, d;
        int o = h << 3;
        a = r[o+0]; d = pk_sub(a, r[o+4]); r[o+0] = pk_add(a, r[o+4]); r[o+4] = d;
        a = r[o+1]; d = pk_sub(a, r[o+5]); r[o+1] = pk_add(a, r[o+5]); r[o+5] = cmulc(d, RS2, -RS2);
        a = r[o+2]; d = pk_sub(a, r[o+6]); r[o+2] = pk_add(a, r[o+6]); r[o+6] = (v2){d.y, -d.x};
        a = r[o+3]; d = pk_sub(a, r[o+7]); r[o+3] = pk_add(a, r[o+7]); r[o+7] = cmulc(d, -RS2, -RS2);
    }
    // stages m=2,1 per consecutive quad
    #pragma unroll
    for (int q = 0; q < 4; ++q) fft4_dif0(r + (q << 2));
}

// Fused rfft-unpack + product + irfft-pretwiddle (R6-verified formulas).
static __device__ __forceinline__ void pair_slot(v2* zz, int j) {
    const int k  = REV13(j);
    const int kp = (N1 - k) & (N1 - 1);
    const int j2 = REV13(kp);
    v2 A = zz[SLOT(j)], B = zz[SLOT(j2)];
    v2 C = zz[N1 + SLOT(j)], D = zz[N1 + SLOT(j2)];
    v2 E  = (v2){0.5f * (A.x + B.x),  0.5f * (A.y - B.y)};
    v2 O  = (v2){0.5f * (A.y + B.y), -0.5f * (A.x - B.x)};
    v2 F  = (v2){0.5f * (C.x + D.x),  0.5f * (C.y - D.y)};
    v2 Ov = (v2){0.5f * (C.y + D.y), -0.5f * (C.x - D.x)};
    v2 Tm = expi(-PI_F * (float)k * (1.f / 8192.f));
    v2 u = cmul(Tm, O), v = cmul(Tm, Ov);
    v2 G = cmul(pk_add(E, u), pk_add(F, v));
    v2 H = cmul(pk_sub(E, u), pk_sub(F, v));
    v2 S  = (v2){0.5f * (G.x + H.x), 0.5f * (G.y + H.y)};
    v2 gh = pk_sub(G, H);
    v2 t2 = cmul((v2){Tm.x, -Tm.y}, gh);
    v2 Dv = (v2){-0.5f * t2.y, 0.5f * t2.x};
    zz[SLOT(j)]  = pk_add(S, Dv);
    zz[SLOT(j2)] = (v2){S.x - Dv.x, -(S.y - Dv.y)};
}

__launch_bounds__(BLOCK, 4)
__global__ void cbp_fft_kernel(const float* __restrict__ x1,
                               const float* __restrict__ x2,
                               const int* __restrict__ h1,
                               const float* __restrict__ s1,
                               float* __restrict__ out) {
    __shared__ v2 zz[2 * N1];   // c1 | c2, 128 KB
    const int tid = threadIdx.x;
    const int l   = tid & 63;
    const int b   = blockIdx.x;
    float* zf = (float*)zz;

    // ---- zero both sketches (float4 wide stores) ----
    {
        float4* z4 = (float4*)zz;
        #pragma unroll
        for (int j = 0; j < 8; ++j) z4[tid + (j << 10)] = make_float4(0.f, 0.f, 0.f, 0.f);
    }
    __syncthreads();

    // ---- count-sketch scatter (random buckets: full SLOT) ----
    const float* x1r = x1 + (size_t)b * DIM;
    const float* x2r = x2 + (size_t)b * DIM;
    #pragma unroll
    for (int i = 0; i < DIM / BLOCK; ++i) {
        int d = tid + (i << 10);
        float s = s1[d];
        int   h = h1[d];
        int  fi = (SLOT(h >> 1) << 1) | (h & 1);
        atomicAdd(&zf[fi], s * x1r[d]);
        atomicAdd(&zf[2 * N1 + fi], s * x2r[d]);
    }
    __syncthreads();

    // ======== forward: two independent 8192-pt DIF FFTs ========
    const int half = tid >> 9;
    const int tt   = tid & 511;
    const int hw   = tt >> 6;        // half-wave index 0..7
    v2* Ah = zz + half * N1;

    // P1 (S=1024): slot(k + j*1024) = (k ^ ((k>>4)&15)) + j*1024
    #pragma unroll 1
    for (int q = 0; q < 2; ++q) {
        int k  = tt + (q << 9);
        int bs = k ^ ((k >> 4) & 15);
        v2 r[8];
        #pragma unroll
        for (int j = 0; j < 8; ++j) r[j] = Ah[bs + (j << 10)];
        fft8_dif(r, (float)k * (-PI_F / 4096.f));
        #pragma unroll
        for (int j = 0; j < 8; ++j) Ah[bs + (j << 10)] = r[j];
    }
    __syncthreads();

    // P2 (S=128, wave-private): slot = (bE ^ 8*(j&1)) + 128j
    #pragma unroll 1
    for (int q = 0; q < 2; ++q) {
        int kk = (tt & 63) + (q << 6);
        int bE = ((hw << 10) + kk) ^ (kk >> 4);
        int bO = bE ^ 8;
        v2 r[8];
        #pragma unroll
        for (int j = 0; j < 8; ++j) r[j] = Ah[((j & 1) ? bO : bE) + (j << 7)];
        fft8_dif(r, (float)kk * (-PI_F / 512.f));
        #pragma unroll
        for (int j = 0; j < 8; ++j) Ah[((j & 1) ? bO : bE) + (j << 7)] = r[j];
    }
    WAVE_FENCE();

    // P3 (S=16, wave-private, conflict-free): slot = (a0 ^ j) + 16j
    #pragma unroll 1
    for (int q = 0; q < 2; ++q) {
        int g  = (hw << 3) + ((l >> 4) << 1) + q;
        int kf = l & 15;
        int a0 = (g << 7) + (kf ^ (q << 3));
        v2 r[8];
        #pragma unroll
        for (int j = 0; j < 8; ++j) r[j] = Ah[(a0 ^ j) + (j << 4)];
        fft8_dif(r, (float)kf * (-PI_F / 64.f));
        #pragma unroll
        for (int j = 0; j < 8; ++j) Ah[(a0 ^ j) + (j << 4)] = r[j];
    }
    WAVE_FENCE();

    // P4+P5 fused: 16-pt DIF on thread-private 16-span, slot = sbase ^ i
    {
        const int span  = (hw << 6) + (l & 15) + ((l >> 4) << 4);
        const int sbase = (span << 4) + (span & 15);
        v2 r[16];
        #pragma unroll
        for (int i = 0; i < 16; ++i) r[i] = Ah[sbase ^ i];
        fft16_dif0(r);
        #pragma unroll
        for (int i = 0; i < 16; ++i) Ah[sbase ^ i] = r[i];
    }
    __syncthreads();

    // ======== fused pairing (R6-verified) ========
    #pragma unroll 1
    for (int i = 0; i < 4; ++i) pair_slot(zz, (tid + (i << 10)) << 1);
    if (tid == 0) pair_slot(zz, 1);   // k = 4096 self-pair position
    __syncthreads();

    // ======== inverse: one 8192-pt DIT IFFT ========
    // P1' (S=1, thread-private 8-span): slot(tid*8+i) = B1 ^ i
    {
        int B1 = (tid << 3) ^ ((tid >> 1) & 15);
        v2 r[8];
        #pragma unroll
        for (int i = 0; i < 8; ++i) r[i] = zz[B1 ^ i];
        fft8_dit0(r);
        #pragma unroll
        for (int i = 0; i < 8; ++i) zz[B1 ^ i] = r[i];
    }
    WAVE_FENCE();
    // P2' (S=8, wave-private) — full SLOT
    {
        int g = tid >> 3, k = tid & 7;
        int base = (g << 6) + k;
        v2 r[8];
        #pragma unroll
        for (int j = 0; j < 8; ++j) r[j] = zz[SLOT(base + (j << 3))];
        fft8_dit(r, (float)k * (PI_F / 32.f));
        #pragma unroll
        for (int j = 0; j < 8; ++j) zz[SLOT(base + (j << 3))] = r[j];
    }
    WAVE_FENCE();
    // P3' (S=64, wave-private): 4 bases + 64j immediates
    {
        int k = tid & 63;
        int base0 = ((tid >> 6) << 9) + (k & ~15);
        int Kh = k >> 4, K15 = k & 15;
        int B0  = base0 + (K15 ^ Kh);
        int Bm1 = base0 + (K15 ^ (Kh + 4));
        int Bm2 = base0 + (K15 ^ (Kh + 8));
        int Bm3 = base0 + (K15 ^ (Kh + 12));
        v2 r[8];
        r[0] = zz[B0];        r[1] = zz[Bm1 + 64];
        r[2] = zz[Bm2 + 128]; r[3] = zz[Bm3 + 192];
        r[4] = zz[B0 + 256];  r[5] = zz[Bm1 + 320];
        r[6] = zz[Bm2 + 384]; r[7] = zz[Bm3 + 448];
        fft8_dit(r, (float)k * (PI_F / 256.f));
        zz[B0]        = r[0]; zz[Bm1 + 64]  = r[1];
        zz[Bm2 + 128] = r[2]; zz[Bm3 + 192] = r[3];
        zz[B0 + 256]  = r[4]; zz[Bm1 + 320] = r[5];
        zz[Bm2 + 384] = r[6]; zz[Bm3 + 448] = r[7];
    }
    __syncthreads();
    // P4' (S=512): slot = ((g*4096+k) ^ ((k>>4)&15)) + 512j
    {
        int g = tid >> 9, k = tid & 511;
        int bp = ((g << 12) + k) ^ ((k >> 4) & 15);
        v2 r[8];
        #pragma unroll
        for (int j = 0; j < 8; ++j) r[j] = zz[bp + (j << 9)];
        fft8_dit(r, (float)k * (PI_F / 2048.f));
        #pragma unroll
        for (int j = 0; j < 8; ++j) zz[bp + (j << 9)] = r[j];
    }
    __syncthreads();

    // P5': final radix-2 + coalesced float4 stores.
    // slot(tid*4+d) = b5 ^ d (XOR — R8 fix); slot(n+4096) = slot(n) + 4096.
    float* outr = out + (size_t)b * (2 * N1);
    const float inv_n1 = 1.0f / (float)N1;
    const int b5 = (tid << 2) ^ ((tid >> 2) & 15);
    #pragma unroll 1
    for (int i = 0; i < 2; ++i) {
        v2 lo[2], hi[2];
        #pragma unroll
        for (int s2 = 0; s2 < 2; ++s2) {
            int d5 = (i << 1) + s2;
            int n  = (tid << 2) + d5;
            v2 a  = zz[b5 ^ d5];
            v2 bb = zz[(b5 ^ d5) + 4096];
            v2 T  = expi(PI_F * (float)n * (1.f / 4096.f));
            v2 tb = cmul(T, bb);
            lo[s2] = pk_add(a, tb);
            hi[s2] = pk_sub(a, tb);
        }
        float4 vlo = make_float4(lo[0].x * inv_n1, lo[0].y * inv_n1,
                                 lo[1].x * inv_n1, lo[1].y * inv_n1);
        float4 vhi = make_float4(hi[0].x * inv_n1, hi[0].y * inv_n1,
                                 hi[1].x * inv_n1, hi[1].y * inv_n1);
        *(float4*)(outr + (tid << 3) + (i << 2)) = vlo;
        *(float4*)(outr + N1 + (tid << 3) + (i << 2)) = vhi;
    }
}

extern "C" void kernel_launch(void* const* d_in, const int* in_sizes, int n_in,
                              void* d_out, int out_size, void* d_ws, size_t ws_size,
                              hipStream_t stream) {
    const float* x1 = (const float*)d_in[0];
    const float* x2 = (const float*)d_in[1];
    const int*   h1 = (const int*)d_in[2];
    const float* s1 = (const float*)d_in[3];
    float* out = (float*)d_out;
    const int B = in_sizes[0] / DIM;   // 256
    cbp_fft_kernel<<<B, BLOCK, 0, stream>>>(x1, x2, h1, s1, out);
}